// Round 3
// baseline (1637.359 us; speedup 1.0000x reference)
//
#include <hip/hip_runtime.h>
#include <hip/hip_fp16.h>
#include <math.h>

#define N_    16
#define CIN_  256
#define DIM_  32
#define H_    128
#define W_    128
#define P_    (H_*W_)          // 16384
#define A_    192
#define R_    192
#define AR_   (A_*R_)          // 36864
#define CSR_CAP 18432          // per-angle pixlist capacity (16384 + 192*3 pad, rounded)
#define NWORD 16520            // LDS 8-byte words: 128*129=16512 data + sentinel @16512
#define SENT  16512            // swizzled sentinel word (zero slot)

// 4 fp16 channels per pixel, one ds_read_b64
struct alignas(8) h4 { __half2 a, b; };

// swizzled word index for pixel p: y*129 + (x ^ ((y&7)<<2))
__device__ __forceinline__ int swz(int p) {
    int y = p >> 7, x = p & 127;
    return y * 129 + (x ^ ((y & 7) << 2));
}

// ---------------- CSR build: per-angle pixel lists sorted by rho -----------
__global__ __launch_bounds__(256) void csr_build(
        unsigned short* __restrict__ pix, int* __restrict__ offg) {
    int a = blockIdx.x;
    __shared__ int cnt[192];
    __shared__ int off[193];
    __shared__ unsigned char rho_s[P_];       // 16 KB
    double theta = (double)a * (M_PI / 192.0);
    double irho  = 182.0 / 191.0;
    double ts = sin(theta) / irho;
    double tc = cos(theta) / irho;
    for (int i = threadIdx.x; i < 192; i += 256) cnt[i] = 0;
    __syncthreads();
    for (int p = threadIdx.x; p < P_; p += 256) {
        int y = p >> 7, x = p & 127;
        double v = __dadd_rn(__dmul_rn((double)(x - 64), tc),
                             __dmul_rn((double)(y - 64), ts));
        int r = (int)rint(v) + 96;
        r = r < 0 ? 0 : (r > 191 ? 191 : r);
        rho_s[p] = (unsigned char)r;
        atomicAdd(&cnt[r], 1);
    }
    __syncthreads();
    if (threadIdx.x == 0) {
        int run = 0;
        for (int r = 0; r < 192; ++r) { off[r] = run; run += (cnt[r] + 3) & ~3; }
        off[192] = run;
    }
    __syncthreads();
    if (threadIdx.x < 193) offg[a * 193 + threadIdx.x] = off[threadIdx.x];
    for (int i = threadIdx.x; i < 192; i += 256) cnt[i] = off[i];
    __syncthreads();
    unsigned short* pa = pix + (size_t)a * CSR_CAP;
    for (int p = threadIdx.x; p < P_; p += 256) {
        int idx = atomicAdd(&cnt[rho_s[p]], 1);
        pa[idx] = (unsigned short)swz(p);     // pre-swizzled word index
    }
    __syncthreads();
    for (int r = threadIdx.x; r < 192; r += 256)
        for (int j = cnt[r]; j < off[r + 1]; ++j) pa[j] = SENT;  // sentinel
}

// ---------------- 1x1 conv + bias: 4 pixels/thread via float4 --------------
// 256 blocks x 256 threads; acc = float4[32] (128 VGPR) -> deep ILP at low
// occupancy; dwordx4 loads = 1 KB/wave-instr.
__global__ __launch_bounds__(256) void conv1x1_kernel(
        const float* __restrict__ x, const float* __restrict__ w,
        const float* __restrict__ b, float* __restrict__ out) {
    int g = blockIdx.x * 256 + threadIdx.x;   // 0..65535
    int n = g >> 12;                          // 4096 float4 per image plane
    int q = g & 4095;
    const float4* xp = (const float4*)(x + (size_t)n * CIN_ * P_) + q;
    float4 acc[DIM_];
    #pragma unroll
    for (int co = 0; co < DIM_; ++co) {
        float bb = b[co];
        acc[co] = make_float4(bb, bb, bb, bb);
    }
    for (int ci = 0; ci < CIN_; ++ci) {
        float4 v = xp[(size_t)ci * (P_ / 4)];
        #pragma unroll
        for (int co = 0; co < DIM_; ++co) {
            float ww = w[co * CIN_ + ci];
            acc[co].x += v.x * ww;
            acc[co].y += v.y * ww;
            acc[co].z += v.z * ww;
            acc[co].w += v.w * ww;
        }
    }
    float4* op = (float4*)(out + (size_t)n * DIM_ * P_) + q;
    #pragma unroll
    for (int co = 0; co < DIM_; ++co) op[(size_t)co * (P_ / 4)] = acc[co];
}

// ---------------- per-channel sum / sumsq over [NC][S] slabs ---------------
__global__ __launch_bounds__(256) void stats_kernel(
        const float* __restrict__ in, int S,
        double* __restrict__ dsum, double* __restrict__ dsq) {
    int c = blockIdx.x & 31;
    const float* p = in + (size_t)blockIdx.x * S;
    double s = 0.0, q = 0.0;
    for (int i = threadIdx.x; i < S; i += 256) {
        double v = (double)p[i];
        s += v; q += v * v;
    }
    #pragma unroll
    for (int off = 32; off > 0; off >>= 1) {
        s += __shfl_down(s, off, 64);
        q += __shfl_down(q, off, 64);
    }
    __shared__ double ls[4], lq[4];
    int wv = threadIdx.x >> 6;
    if ((threadIdx.x & 63) == 0) { ls[wv] = s; lq[wv] = q; }
    __syncthreads();
    if (threadIdx.x == 0) {
        s = ls[0] + ls[1] + ls[2] + ls[3];
        q = lq[0] + lq[1] + lq[2] + lq[3];
        atomicAdd(&dsum[c], s);
        atomicAdd(&dsq[c], q);
    }
}

// ---------------- finalize BN: scale/shift per channel ---------------------
__global__ void fin_kernel(const double* __restrict__ dsum, const double* __restrict__ dsq,
                           const float* __restrict__ g, const float* __restrict__ be,
                           double cnt, float* __restrict__ scsh) {
    int c = threadIdx.x;
    if (c < 32) {
        double m = dsum[c] / cnt;
        double v = dsq[c] / cnt - m * m;
        double rstd = 1.0 / sqrt(v + 1e-5);
        double sc = (double)g[c] * rstd;
        scsh[c]      = (float)sc;
        scsh[32 + c] = (float)((double)be[c] - m * sc);
    }
}

// ---------------- DHT gather: feat(pre-BN) -> acc[n,c,192,192] -------------
// 256 blocks x 1024 threads. Block = (channel-quad, angle-half).
// ONE ds_read_b64 per pixel serves 4 fp16 channels. Accumulation: 4-pixel
// v_pk_add_f16 trees (2 ch/instr) flushed to fp32 via fma_mix (*one trick).
__global__ __launch_bounds__(1024) void dht_gather(
        const float* __restrict__ feat, const unsigned short* __restrict__ pix,
        const int* __restrict__ offg, const float* __restrict__ scsh,
        float one, float* __restrict__ acc) {
    extern __shared__ h4 d[];                 // NWORD * 8 B = 132160 B
    int quad = blockIdx.x >> 1, ah = blockIdx.x & 1;
    int nc0 = quad * 4;
    {
        int cb = nc0 & 31;                    // channels cb..cb+3
        float s0 = scsh[cb],     h0 = scsh[32 + cb];
        float s1 = scsh[cb + 1], h1 = scsh[33 + cb];
        float s2 = scsh[cb + 2], h2 = scsh[34 + cb];
        float s3 = scsh[cb + 3], h3 = scsh[35 + cb];
        const float4* f0p = (const float4*)(feat + (size_t)(nc0 + 0) * P_);
        const float4* f1p = (const float4*)(feat + (size_t)(nc0 + 1) * P_);
        const float4* f2p = (const float4*)(feat + (size_t)(nc0 + 2) * P_);
        const float4* f3p = (const float4*)(feat + (size_t)(nc0 + 3) * P_);
        for (int q = threadIdx.x; q < P_ / 4; q += 1024) {
            float4 a0 = f0p[q], a1 = f1p[q], a2 = f2p[q], a3 = f3p[q];
            int p = q * 4;
            int base = swz(p);                // 4-group stays contiguous
            h4 w;
            w.a = __halves2half2(__float2half(fmaxf(a0.x * s0 + h0, 0.f)),
                                 __float2half(fmaxf(a1.x * s1 + h1, 0.f)));
            w.b = __halves2half2(__float2half(fmaxf(a2.x * s2 + h2, 0.f)),
                                 __float2half(fmaxf(a3.x * s3 + h3, 0.f)));
            d[base + 0] = w;
            w.a = __halves2half2(__float2half(fmaxf(a0.y * s0 + h0, 0.f)),
                                 __float2half(fmaxf(a1.y * s1 + h1, 0.f)));
            w.b = __halves2half2(__float2half(fmaxf(a2.y * s2 + h2, 0.f)),
                                 __float2half(fmaxf(a3.y * s3 + h3, 0.f)));
            d[base + 1] = w;
            w.a = __halves2half2(__float2half(fmaxf(a0.z * s0 + h0, 0.f)),
                                 __float2half(fmaxf(a1.z * s1 + h1, 0.f)));
            w.b = __halves2half2(__float2half(fmaxf(a2.z * s2 + h2, 0.f)),
                                 __float2half(fmaxf(a3.z * s3 + h3, 0.f)));
            d[base + 2] = w;
            w.a = __halves2half2(__float2half(fmaxf(a0.w * s0 + h0, 0.f)),
                                 __float2half(fmaxf(a1.w * s1 + h1, 0.f)));
            w.b = __halves2half2(__float2half(fmaxf(a2.w * s2 + h2, 0.f)),
                                 __float2half(fmaxf(a3.w * s3 + h3, 0.f)));
            d[base + 3] = w;
        }
        if (threadIdx.x < 8) {                // zero sentinel words
            *(uint2*)&d[SENT + threadIdx.x] = make_uint2(0u, 0u);
        }
    }
    __syncthreads();
    int abase = ah * 96;
    for (int it = 0; it < 18; ++it) {
        int seg = it * 1024 + threadIdx.x;    // 0..18431 (96 angles x 192 rho)
        int al = seg / 192, r = seg - al * 192;
        int a = abase + al;
        int o0 = offg[a * 193 + r];
        int o1 = offg[a * 193 + r + 1];
        const unsigned short* pl = pix + (size_t)a * CSR_CAP;
        float s0 = 0.f, s1 = 0.f, s2 = 0.f, s3 = 0.f;
        int j = o0;
        for (; j + 8 <= o1; j += 8) {
            ushort4 ua = *(const ushort4*)(pl + j);
            ushort4 ub = *(const ushort4*)(pl + j + 4);
            h4 v0 = d[ua.x];
            h4 v1 = d[ua.y];
            h4 v2 = d[ua.z];
            h4 v3 = d[ua.w];
            h4 v4 = d[ub.x];
            h4 v5 = d[ub.y];
            h4 v6 = d[ub.z];
            h4 v7 = d[ub.w];
            // 4-px pk_add trees, flush to f32 (fma_mix via *one)
            __half2 ta = __hadd2(__hadd2(v0.a, v1.a), __hadd2(v2.a, v3.a));
            __half2 tb = __hadd2(__hadd2(v0.b, v1.b), __hadd2(v2.b, v3.b));
            s0 += __low2float(ta) * one; s1 += __high2float(ta) * one;
            s2 += __low2float(tb) * one; s3 += __high2float(tb) * one;
            ta = __hadd2(__hadd2(v4.a, v5.a), __hadd2(v6.a, v7.a));
            tb = __hadd2(__hadd2(v4.b, v5.b), __hadd2(v6.b, v7.b));
            s0 += __low2float(ta) * one; s1 += __high2float(ta) * one;
            s2 += __low2float(tb) * one; s3 += __high2float(tb) * one;
        }
        if (j < o1) {                          // padded: remainder is exactly 4
            ushort4 ua = *(const ushort4*)(pl + j);
            h4 v0 = d[ua.x];
            h4 v1 = d[ua.y];
            h4 v2 = d[ua.z];
            h4 v3 = d[ua.w];
            __half2 ta = __hadd2(__hadd2(v0.a, v1.a), __hadd2(v2.a, v3.a));
            __half2 tb = __hadd2(__hadd2(v0.b, v1.b), __hadd2(v2.b, v3.b));
            s0 += __low2float(ta) * one; s1 += __high2float(ta) * one;
            s2 += __low2float(tb) * one; s3 += __high2float(tb) * one;
        }
        size_t ob = (size_t)nc0 * AR_ + (size_t)a * R_ + r;
        acc[ob]           = s0;
        acc[ob + AR_]     = s1;
        acc[ob + 2 * AR_] = s2;
        acc[ob + 3 * AR_] = s3;
    }
}

// ---------------- 3x3 conv (+optional input BN+ReLU) + bias ----------------
// 16x32 tile, 2 output rows/thread, single-barrier LDS double-buffer:
// prefetch ci+1 to regs -> 576 FMAs hide HBM latency -> write buf^1 -> sync.
template <bool BN>
__global__ __launch_bounds__(256) void conv3x3_kernel(
        const float* __restrict__ in, const float* __restrict__ w,
        const float* __restrict__ b,
        const float* __restrict__ sc, const float* __restrict__ sh,
        float* __restrict__ out) {
    __shared__ float tile[2][34][20];         // 5440 B
    int tx = threadIdx.x & 15, ty = threadIdx.x >> 4;   // ty in [0,16)
    int x0 = blockIdx.x * 16, y0 = blockIdx.y * 32, n = blockIdx.z;
    int tid = threadIdx.x;

    float acc0[DIM_], acc1[DIM_];
    #pragma unroll
    for (int co = 0; co < DIM_; ++co) { acc0[co] = b[co]; acc1[co] = b[co]; }

    // halo loader: element t (0..611) of channel ci, BN applied if enabled
    auto ld = [&](int ci, int t) -> float {
        int ly = t / 18, lx = t - ly * 18;
        int gy = y0 - 1 + ly, gx = x0 - 1 + lx;
        float v = 0.f;
        if (gy >= 0 && gy < 192 && gx >= 0 && gx < 192) {
            v = in[((size_t)(n * DIM_ + ci)) * AR_ + gy * 192 + gx];
            if (BN) v = fmaxf(v * sc[ci] + sh[ci], 0.f);
        }
        return v;
    };
    auto st = [&](int buf, int t, float v) {
        int ly = t / 18, lx = t - ly * 18;
        tile[buf][ly][lx] = v;
    };

    // prologue: stage ci=0 into buf 0
    {
        float r0 = ld(0, tid), r1 = ld(0, tid + 256);
        float r2 = (tid < 100) ? ld(0, tid + 512) : 0.f;
        st(0, tid, r0); st(0, tid + 256, r1);
        if (tid < 100) st(0, tid + 512, r2);
    }
    __syncthreads();

    for (int ci = 0; ci < DIM_; ++ci) {
        int cur = ci & 1, nxt = cur ^ 1;
        float p0 = 0.f, p1 = 0.f, p2 = 0.f;
        if (ci + 1 < DIM_) {                  // issue next-channel loads early
            p0 = ld(ci + 1, tid);
            p1 = ld(ci + 1, tid + 256);
            if (tid < 100) p2 = ld(ci + 1, tid + 512);
        }
        // compute from tile[cur]: rows 2ty..2ty+3, cols tx..tx+2
        float v[4][3];
        #pragma unroll
        for (int rr = 0; rr < 4; ++rr)
            #pragma unroll
            for (int cc = 0; cc < 3; ++cc)
                v[rr][cc] = tile[cur][2 * ty + rr][tx + cc];
        const float* wp = w + ci * 9;         // w[co][ci][k]: co stride 288
        #pragma unroll
        for (int co = 0; co < DIM_; ++co) {
            #pragma unroll
            for (int k = 0; k < 9; ++k) {
                float ww = wp[co * 288 + k];
                acc0[co] += v[k / 3][k % 3] * ww;
                acc1[co] += v[k / 3 + 1][k % 3] * ww;
            }
        }
        if (ci + 1 < DIM_) {                  // write prefetched channel
            st(nxt, tid, p0); st(nxt, tid + 256, p1);
            if (tid < 100) st(nxt, tid + 512, p2);
        }
        __syncthreads();
    }

    int oy = y0 + 2 * ty;
    size_t o = ((size_t)(n * DIM_) * 192 + oy) * 192 + x0 + tx;
    #pragma unroll
    for (int co = 0; co < DIM_; ++co) {
        out[o + (size_t)co * AR_]       = acc0[co];
        out[o + 192 + (size_t)co * AR_] = acc1[co];
    }
}

// ---------------- final BN + ReLU -> d_out ---------------------------------
__global__ __launch_bounds__(256) void bnrelu_kernel(
        const float* __restrict__ in, const float* __restrict__ scsh,
        float* __restrict__ out) {
    int i = blockIdx.x * 256 + threadIdx.x;   // float4 index, total 4718592
    if (i >= 4718592) return;
    int c = (i / 9216) & 31;                  // 9216 float4 per channel slab
    float sc = scsh[c], sh = scsh[32 + c];
    float4 v = ((const float4*)in)[i];
    v.x = fmaxf(v.x * sc + sh, 0.f);
    v.y = fmaxf(v.y * sc + sh, 0.f);
    v.z = fmaxf(v.z * sc + sh, 0.f);
    v.w = fmaxf(v.w * sc + sh, 0.f);
    ((float4*)out)[i] = v;
}

extern "C" void kernel_launch(void* const* d_in, const int* in_sizes, int n_in,
                              void* d_out, int out_size, void* d_ws, size_t ws_size,
                              hipStream_t stream) {
    const float* x   = (const float*)d_in[0];
    const float* w1  = (const float*)d_in[1];
    const float* b1  = (const float*)d_in[2];
    const float* g1  = (const float*)d_in[3];
    const float* be1 = (const float*)d_in[4];
    const float* w2  = (const float*)d_in[5];
    const float* b2  = (const float*)d_in[6];
    const float* g2  = (const float*)d_in[7];
    const float* be2 = (const float*)d_in[8];
    const float* w3  = (const float*)d_in[9];
    const float* b3  = (const float*)d_in[10];
    const float* g3  = (const float*)d_in[11];
    const float* be3 = (const float*)d_in[12];
    float* out = (float*)d_out;

    char* ws = (char*)d_ws;
    float* bufA = (float*)(ws);                       // [0, 75497472)
    unsigned short* pix = (unsigned short*)(ws + 33554432);   // 7,077,888 B
    int*   offg  = (int*)(ws + 40632320);                     // 148,224 B
    float* bufB  = (float*)(ws + 75497472);                   // 75,497,472 B
    double* stats = (double*)(ws + 150994944);                // 1536 B
    float*  scsh  = (float*)(ws + 150996480);                 // 768 B

    hipMemsetAsync(stats, 0, 192 * sizeof(double), stream);
    csr_build<<<192, 256, 0, stream>>>(pix, offg);

    // stage 1: 1x1 conv -> bufA (pre-BN), stats, finalize
    conv1x1_kernel<<<256, 256, 0, stream>>>(x, w1, b1, bufA);
    stats_kernel<<<512, 256, 0, stream>>>(bufA, P_, stats + 0, stats + 32);
    fin_kernel<<<1, 64, 0, stream>>>(stats + 0, stats + 32, g1, be1,
                                     (double)(N_ * P_), scsh);

    // stage 2: DHT gather (BN1+ReLU+fp16 pack while staging to LDS) -> bufB
    hipFuncSetAttribute((const void*)dht_gather,
                        hipFuncAttributeMaxDynamicSharedMemorySize,
                        NWORD * sizeof(h4));
    dht_gather<<<256, 1024, NWORD * sizeof(h4), stream>>>(
        bufA, pix, offg, scsh, 1.0f, bufB);

    // stage 3: conv2 (raw input) -> bufA, stats, finalize
    conv3x3_kernel<false><<<dim3(12, 6, 16), 256, 0, stream>>>(
        bufB, w2, b2, nullptr, nullptr, bufA);
    stats_kernel<<<512, 256, 0, stream>>>(bufA, AR_, stats + 64, stats + 96);
    fin_kernel<<<1, 64, 0, stream>>>(stats + 64, stats + 96, g2, be2,
                                     (double)(N_ * AR_), scsh + 64);

    // stage 4: conv3 (BN2+ReLU on the fly) -> bufB, stats, finalize
    conv3x3_kernel<true><<<dim3(12, 6, 16), 256, 0, stream>>>(
        bufA, w3, b3, scsh + 64, scsh + 96, bufB);
    stats_kernel<<<512, 256, 0, stream>>>(bufB, AR_, stats + 128, stats + 160);
    fin_kernel<<<1, 64, 0, stream>>>(stats + 128, stats + 160, g3, be3,
                                     (double)(N_ * AR_), scsh + 128);

    // epilogue: BN3 + ReLU -> out
    bnrelu_kernel<<<18432, 256, 0, stream>>>(bufB, scsh + 128, out);
}

// Round 4
// 1456.125 us; speedup vs baseline: 1.1245x; 1.1245x over previous
//
#include <hip/hip_runtime.h>
#include <hip/hip_fp16.h>
#include <math.h>

#define N_    16
#define CIN_  256
#define DIM_  32
#define H_    128
#define W_    128
#define P_    (H_*W_)          // 16384
#define A_    192
#define R_    192
#define AR_   (A_*R_)          // 36864
#define CSR_CAP 18432          // per-angle pixlist capacity (16384 + 192*3 pad, rounded)
#define NWORD 16520            // LDS 8-byte words: 128*129=16512 data + sentinel @16512
#define SENT  16512            // swizzled sentinel word (zero slot)

// 4 fp16 channels per pixel, one ds_read_b64
struct alignas(8) h4 { __half2 a, b; };

// swizzled word index for pixel p: y*129 + (x ^ ((y&7)<<2))
__device__ __forceinline__ int swz(int p) {
    int y = p >> 7, x = p & 127;
    return y * 129 + (x ^ ((y & 7) << 2));
}

// ---------------- CSR build: per-angle pixel lists sorted by rho -----------
__global__ __launch_bounds__(256) void csr_build(
        unsigned short* __restrict__ pix, int* __restrict__ offg) {
    int a = blockIdx.x;
    __shared__ int cnt[192];
    __shared__ int off[193];
    __shared__ unsigned char rho_s[P_];       // 16 KB
    double theta = (double)a * (M_PI / 192.0);
    double irho  = 182.0 / 191.0;
    double ts = sin(theta) / irho;
    double tc = cos(theta) / irho;
    for (int i = threadIdx.x; i < 192; i += 256) cnt[i] = 0;
    __syncthreads();
    for (int p = threadIdx.x; p < P_; p += 256) {
        int y = p >> 7, x = p & 127;
        double v = __dadd_rn(__dmul_rn((double)(x - 64), tc),
                             __dmul_rn((double)(y - 64), ts));
        int r = (int)rint(v) + 96;
        r = r < 0 ? 0 : (r > 191 ? 191 : r);
        rho_s[p] = (unsigned char)r;
        atomicAdd(&cnt[r], 1);
    }
    __syncthreads();
    if (threadIdx.x == 0) {
        int run = 0;
        for (int r = 0; r < 192; ++r) { off[r] = run; run += (cnt[r] + 3) & ~3; }
        off[192] = run;
    }
    __syncthreads();
    if (threadIdx.x < 193) offg[a * 193 + threadIdx.x] = off[threadIdx.x];
    for (int i = threadIdx.x; i < 192; i += 256) cnt[i] = off[i];
    __syncthreads();
    unsigned short* pa = pix + (size_t)a * CSR_CAP;
    for (int p = threadIdx.x; p < P_; p += 256) {
        int idx = atomicAdd(&cnt[rho_s[p]], 1);
        pa[idx] = (unsigned short)swz(p);     // pre-swizzled word index
    }
    __syncthreads();
    for (int r = threadIdx.x; r < 192; r += 256)
        for (int j = cnt[r]; j < off[r + 1]; ++j) pa[j] = SENT;  // sentinel
}

// ---------------- 1x1 conv + bias: x[16,256,128,128] -> pre[16,32,128,128] -
// (R2 known-good form: 1024 blocks x 256, 1 px/thread, 16 waves/CU)
__global__ __launch_bounds__(256) void conv1x1_kernel(
        const float* __restrict__ x, const float* __restrict__ w,
        const float* __restrict__ b, float* __restrict__ out) {
    int g = blockIdx.x * 256 + threadIdx.x;   // 0..262143  (N*P)
    int n = g >> 14, p = g & (P_ - 1);
    const float* xp = x + (size_t)n * CIN_ * P_ + p;
    float acc[DIM_];
    #pragma unroll
    for (int co = 0; co < DIM_; ++co) acc[co] = b[co];
    for (int ci = 0; ci < CIN_; ++ci) {
        float v = xp[(size_t)ci * P_];
        #pragma unroll
        for (int co = 0; co < DIM_; ++co)
            acc[co] += v * w[co * CIN_ + ci];
    }
    float* op = out + (size_t)n * DIM_ * P_ + p;
    #pragma unroll
    for (int co = 0; co < DIM_; ++co) op[(size_t)co * P_] = acc[co];
}

// ---------------- per-channel sum / sumsq over [NC][S] slabs ---------------
__global__ __launch_bounds__(256) void stats_kernel(
        const float* __restrict__ in, int S,
        double* __restrict__ dsum, double* __restrict__ dsq) {
    int c = blockIdx.x & 31;
    const float* p = in + (size_t)blockIdx.x * S;
    double s = 0.0, q = 0.0;
    for (int i = threadIdx.x; i < S; i += 256) {
        double v = (double)p[i];
        s += v; q += v * v;
    }
    #pragma unroll
    for (int off = 32; off > 0; off >>= 1) {
        s += __shfl_down(s, off, 64);
        q += __shfl_down(q, off, 64);
    }
    __shared__ double ls[4], lq[4];
    int wv = threadIdx.x >> 6;
    if ((threadIdx.x & 63) == 0) { ls[wv] = s; lq[wv] = q; }
    __syncthreads();
    if (threadIdx.x == 0) {
        s = ls[0] + ls[1] + ls[2] + ls[3];
        q = lq[0] + lq[1] + lq[2] + lq[3];
        atomicAdd(&dsum[c], s);
        atomicAdd(&dsq[c], q);
    }
}

// ---------------- finalize BN: scale/shift per channel ---------------------
__global__ void fin_kernel(const double* __restrict__ dsum, const double* __restrict__ dsq,
                           const float* __restrict__ g, const float* __restrict__ be,
                           double cnt, float* __restrict__ scsh) {
    int c = threadIdx.x;
    if (c < 32) {
        double m = dsum[c] / cnt;
        double v = dsq[c] / cnt - m * m;
        double rstd = 1.0 / sqrt(v + 1e-5);
        double sc = (double)g[c] * rstd;
        scsh[c]      = (float)sc;
        scsh[32 + c] = (float)((double)be[c] - m * sc);
    }
}

// ---------------- DHT gather: feat(pre-BN) -> acc[n,c,192,192] -------------
__global__ __launch_bounds__(1024) void dht_gather(
        const float* __restrict__ feat, const unsigned short* __restrict__ pix,
        const int* __restrict__ offg, const float* __restrict__ scsh,
        float one, float* __restrict__ acc) {
    extern __shared__ h4 d[];                 // NWORD * 8 B = 132160 B
    int quad = blockIdx.x >> 1, ah = blockIdx.x & 1;
    int nc0 = quad * 4;
    {
        int cb = nc0 & 31;                    // channels cb..cb+3
        float s0 = scsh[cb],     h0 = scsh[32 + cb];
        float s1 = scsh[cb + 1], h1 = scsh[33 + cb];
        float s2 = scsh[cb + 2], h2 = scsh[34 + cb];
        float s3 = scsh[cb + 3], h3 = scsh[35 + cb];
        const float4* f0p = (const float4*)(feat + (size_t)(nc0 + 0) * P_);
        const float4* f1p = (const float4*)(feat + (size_t)(nc0 + 1) * P_);
        const float4* f2p = (const float4*)(feat + (size_t)(nc0 + 2) * P_);
        const float4* f3p = (const float4*)(feat + (size_t)(nc0 + 3) * P_);
        for (int q = threadIdx.x; q < P_ / 4; q += 1024) {
            float4 a0 = f0p[q], a1 = f1p[q], a2 = f2p[q], a3 = f3p[q];
            int p = q * 4;
            int base = swz(p);                // 4-group stays contiguous
            h4 w;
            w.a = __halves2half2(__float2half(fmaxf(a0.x * s0 + h0, 0.f)),
                                 __float2half(fmaxf(a1.x * s1 + h1, 0.f)));
            w.b = __halves2half2(__float2half(fmaxf(a2.x * s2 + h2, 0.f)),
                                 __float2half(fmaxf(a3.x * s3 + h3, 0.f)));
            d[base + 0] = w;
            w.a = __halves2half2(__float2half(fmaxf(a0.y * s0 + h0, 0.f)),
                                 __float2half(fmaxf(a1.y * s1 + h1, 0.f)));
            w.b = __halves2half2(__float2half(fmaxf(a2.y * s2 + h2, 0.f)),
                                 __float2half(fmaxf(a3.y * s3 + h3, 0.f)));
            d[base + 1] = w;
            w.a = __halves2half2(__float2half(fmaxf(a0.z * s0 + h0, 0.f)),
                                 __float2half(fmaxf(a1.z * s1 + h1, 0.f)));
            w.b = __halves2half2(__float2half(fmaxf(a2.z * s2 + h2, 0.f)),
                                 __float2half(fmaxf(a3.z * s3 + h3, 0.f)));
            d[base + 2] = w;
            w.a = __halves2half2(__float2half(fmaxf(a0.w * s0 + h0, 0.f)),
                                 __float2half(fmaxf(a1.w * s1 + h1, 0.f)));
            w.b = __halves2half2(__float2half(fmaxf(a2.w * s2 + h2, 0.f)),
                                 __float2half(fmaxf(a3.w * s3 + h3, 0.f)));
            d[base + 3] = w;
        }
        if (threadIdx.x < 8) {                // zero sentinel words
            *(uint2*)&d[SENT + threadIdx.x] = make_uint2(0u, 0u);
        }
    }
    __syncthreads();
    int abase = ah * 96;
    for (int it = 0; it < 18; ++it) {
        int seg = it * 1024 + threadIdx.x;    // 0..18431 (96 angles x 192 rho)
        int al = seg / 192, r = seg - al * 192;
        int a = abase + al;
        int o0 = offg[a * 193 + r];
        int o1 = offg[a * 193 + r + 1];
        const unsigned short* pl = pix + (size_t)a * CSR_CAP;
        float s0 = 0.f, s1 = 0.f, s2 = 0.f, s3 = 0.f;
        int j = o0;
        for (; j + 8 <= o1; j += 8) {
            ushort4 ua = *(const ushort4*)(pl + j);
            ushort4 ub = *(const ushort4*)(pl + j + 4);
            h4 v0 = d[ua.x];
            h4 v1 = d[ua.y];
            h4 v2 = d[ua.z];
            h4 v3 = d[ua.w];
            h4 v4 = d[ub.x];
            h4 v5 = d[ub.y];
            h4 v6 = d[ub.z];
            h4 v7 = d[ub.w];
            __half2 ta = __hadd2(__hadd2(v0.a, v1.a), __hadd2(v2.a, v3.a));
            __half2 tb = __hadd2(__hadd2(v0.b, v1.b), __hadd2(v2.b, v3.b));
            s0 += __low2float(ta) * one; s1 += __high2float(ta) * one;
            s2 += __low2float(tb) * one; s3 += __high2float(tb) * one;
            ta = __hadd2(__hadd2(v4.a, v5.a), __hadd2(v6.a, v7.a));
            tb = __hadd2(__hadd2(v4.b, v5.b), __hadd2(v6.b, v7.b));
            s0 += __low2float(ta) * one; s1 += __high2float(ta) * one;
            s2 += __low2float(tb) * one; s3 += __high2float(tb) * one;
        }
        if (j < o1) {                          // padded: remainder is exactly 4
            ushort4 ua = *(const ushort4*)(pl + j);
            h4 v0 = d[ua.x];
            h4 v1 = d[ua.y];
            h4 v2 = d[ua.z];
            h4 v3 = d[ua.w];
            __half2 ta = __hadd2(__hadd2(v0.a, v1.a), __hadd2(v2.a, v3.a));
            __half2 tb = __hadd2(__hadd2(v0.b, v1.b), __hadd2(v2.b, v3.b));
            s0 += __low2float(ta) * one; s1 += __high2float(ta) * one;
            s2 += __low2float(tb) * one; s3 += __high2float(tb) * one;
        }
        size_t ob = (size_t)nc0 * AR_ + (size_t)a * R_ + r;
        acc[ob]           = s0;
        acc[ob + AR_]     = s1;
        acc[ob + 2 * AR_] = s2;
        acc[ob + 3 * AR_] = s3;
    }
}

// ---------------- 3x3 conv (+optional input BN+ReLU) + bias ----------------
// 16x16 tile, 1 output/thread, acc[32]. Stage 16 CHANNELS per phase into LDS
// (23 KB -> 6 blocks/CU = 24 waves/CU), only 4 barriers/block total. Between
// barriers: 16 x (9 ds_read + 288 FMA) uninterrupted -> deep ILP + TLP.
template <bool BN>
__global__ __launch_bounds__(256) void conv3x3_kernel(
        const float* __restrict__ in, const float* __restrict__ w,
        const float* __restrict__ b,
        const float* __restrict__ sc, const float* __restrict__ sh,
        float* __restrict__ out) {
    __shared__ float tile[16][18][20];        // 23040 B
    int tx = threadIdx.x & 15, ty = threadIdx.x >> 4;
    int x0 = blockIdx.x * 16, y0 = blockIdx.y * 16, n = blockIdx.z;
    float acc[DIM_];
    #pragma unroll
    for (int co = 0; co < DIM_; ++co) acc[co] = b[co];

    for (int half = 0; half < 2; ++half) {
        int cb = half * 16;
        __syncthreads();                      // protect LDS overwrite
        for (int ci = 0; ci < 16; ++ci) {
            const float* src = in + ((size_t)(n * DIM_ + cb + ci)) * AR_;
            float csc = BN ? sc[cb + ci] : 0.f, csh = BN ? sh[cb + ci] : 0.f;
            for (int t = threadIdx.x; t < 324; t += 256) {
                int ly = t / 18, lx = t - ly * 18;
                int gy = y0 - 1 + ly, gx = x0 - 1 + lx;
                float v = 0.f;
                if (gy >= 0 && gy < 192 && gx >= 0 && gx < 192) {
                    v = src[gy * 192 + gx];
                    if (BN) v = fmaxf(v * csc + csh, 0.f);
                }
                tile[ci][ly][lx] = v;
            }
        }
        __syncthreads();
        for (int ci = 0; ci < 16; ++ci) {
            float v[9];
            #pragma unroll
            for (int k = 0; k < 9; ++k) v[k] = tile[ci][ty + k / 3][tx + k % 3];
            const float* wp = w + (cb + ci) * 9;   // w[co][ci][k]: co stride 288
            #pragma unroll
            for (int co = 0; co < DIM_; ++co) {
                #pragma unroll
                for (int k = 0; k < 9; ++k)
                    acc[co] += v[k] * wp[co * 288 + k];
            }
        }
    }
    size_t o = ((size_t)(n * DIM_) * 192 + (y0 + ty)) * 192 + x0 + tx;
    #pragma unroll
    for (int co = 0; co < DIM_; ++co) out[o + (size_t)co * AR_] = acc[co];
}

// ---------------- final BN + ReLU -> d_out ---------------------------------
__global__ __launch_bounds__(256) void bnrelu_kernel(
        const float* __restrict__ in, const float* __restrict__ scsh,
        float* __restrict__ out) {
    int i = blockIdx.x * 256 + threadIdx.x;   // float4 index, total 4718592
    if (i >= 4718592) return;
    int c = (i / 9216) & 31;                  // 9216 float4 per channel slab
    float sc = scsh[c], sh = scsh[32 + c];
    float4 v = ((const float4*)in)[i];
    v.x = fmaxf(v.x * sc + sh, 0.f);
    v.y = fmaxf(v.y * sc + sh, 0.f);
    v.z = fmaxf(v.z * sc + sh, 0.f);
    v.w = fmaxf(v.w * sc + sh, 0.f);
    ((float4*)out)[i] = v;
}

extern "C" void kernel_launch(void* const* d_in, const int* in_sizes, int n_in,
                              void* d_out, int out_size, void* d_ws, size_t ws_size,
                              hipStream_t stream) {
    const float* x   = (const float*)d_in[0];
    const float* w1  = (const float*)d_in[1];
    const float* b1  = (const float*)d_in[2];
    const float* g1  = (const float*)d_in[3];
    const float* be1 = (const float*)d_in[4];
    const float* w2  = (const float*)d_in[5];
    const float* b2  = (const float*)d_in[6];
    const float* g2  = (const float*)d_in[7];
    const float* be2 = (const float*)d_in[8];
    const float* w3  = (const float*)d_in[9];
    const float* b3  = (const float*)d_in[10];
    const float* g3  = (const float*)d_in[11];
    const float* be3 = (const float*)d_in[12];
    float* out = (float*)d_out;

    char* ws = (char*)d_ws;
    float* bufA = (float*)(ws);                       // [0, 75497472)
    unsigned short* pix = (unsigned short*)(ws + 33554432);   // 7,077,888 B
    int*   offg  = (int*)(ws + 40632320);                     // 148,224 B
    float* bufB  = (float*)(ws + 75497472);                   // 75,497,472 B
    double* stats = (double*)(ws + 150994944);                // 1536 B
    float*  scsh  = (float*)(ws + 150996480);                 // 768 B

    hipMemsetAsync(stats, 0, 192 * sizeof(double), stream);
    csr_build<<<192, 256, 0, stream>>>(pix, offg);

    // stage 1: 1x1 conv -> bufA (pre-BN), stats, finalize
    conv1x1_kernel<<<1024, 256, 0, stream>>>(x, w1, b1, bufA);
    stats_kernel<<<512, 256, 0, stream>>>(bufA, P_, stats + 0, stats + 32);
    fin_kernel<<<1, 64, 0, stream>>>(stats + 0, stats + 32, g1, be1,
                                     (double)(N_ * P_), scsh);

    // stage 2: DHT gather (BN1+ReLU+fp16 pack while staging to LDS) -> bufB
    hipFuncSetAttribute((const void*)dht_gather,
                        hipFuncAttributeMaxDynamicSharedMemorySize,
                        NWORD * sizeof(h4));
    dht_gather<<<256, 1024, NWORD * sizeof(h4), stream>>>(
        bufA, pix, offg, scsh, 1.0f, bufB);

    // stage 3: conv2 (raw input) -> bufA, stats, finalize
    conv3x3_kernel<false><<<dim3(12, 12, 16), 256, 0, stream>>>(
        bufB, w2, b2, nullptr, nullptr, bufA);
    stats_kernel<<<512, 256, 0, stream>>>(bufA, AR_, stats + 64, stats + 96);
    fin_kernel<<<1, 64, 0, stream>>>(stats + 64, stats + 96, g2, be2,
                                     (double)(N_ * AR_), scsh + 64);

    // stage 4: conv3 (BN2+ReLU on the fly) -> bufB, stats, finalize
    conv3x3_kernel<true><<<dim3(12, 12, 16), 256, 0, stream>>>(
        bufA, w3, b3, scsh + 64, scsh + 96, bufB);
    stats_kernel<<<512, 256, 0, stream>>>(bufB, AR_, stats + 128, stats + 160);
    fin_kernel<<<1, 64, 0, stream>>>(stats + 128, stats + 160, g3, be3,
                                     (double)(N_ * AR_), scsh + 128);

    // epilogue: BN3 + ReLU -> out
    bnrelu_kernel<<<18432, 256, 0, stream>>>(bufB, scsh + 128, out);
}